// Round 11
// baseline (5565.481 us; speedup 1.0000x reference)
//
#include <hip/hip_runtime.h>
#include <stdint.h>

// Must match numpy float32 rounding exactly: (dx*dx + dy*dy) + dz*dz, no FMA.
#pragma clang fp contract(off)

#define NPT      2048
#define NBATCH   32
#define NPTS     65536
#define MEMBERS  16
#define NGROUPS  (NBATCH / 2)           // 16 groups x 2 batches each
#define NTHREADS 512
#define CHUNK    (NPTS / MEMBERS)       // 4096 points per block per batch
#define PPT      (CHUNK / NTHREADS)     // 8 points per thread per batch
#define WPB      (NTHREADS / 64)        // 8 waves per block
#define LINEPAD  32                     // 256B per (batch,parity) slot line

__device__ __forceinline__ uint32_t f2u(float f) { return __float_as_uint(f); }
__device__ __forceinline__ float u2f(uint32_t u) { return __uint_as_float(u); }

// argmax combine: larger value wins; tie -> smaller index (numpy argmax order)
__device__ __forceinline__ void amerge(float& v, int& i, float ov, int oi) {
    if (ov > v || (ov == v && oi < i)) { v = ov; i = oi; }
}
template<int CTRL>
__device__ __forceinline__ void dpp_round(float& v, int& i) {
    float ov = u2f((uint32_t)__builtin_amdgcn_mov_dpp((int)f2u(v), CTRL, 0xf, 0xf, true));
    int   oi = __builtin_amdgcn_mov_dpp(i, CTRL, 0xf, 0xf, true);
    amerge(v, i, ov, oi);
}
__device__ __forceinline__ void swz16_round(float& v, int& i) {   // lane ^ 16
    float ov = u2f((uint32_t)__builtin_amdgcn_ds_swizzle((int)f2u(v), 0x401F));
    int   oi = __builtin_amdgcn_ds_swizzle(i, 0x401F);
    amerge(v, i, ov, oi);
}
// reduce within each row of 16 lanes (slots/entries replicated per row)
__device__ __forceinline__ void row16_argmax(float& v, int& i) {
    dpp_round<0xB1>(v, i);    // quad_perm xor1
    dpp_round<0x4E>(v, i);    // quad_perm xor2
    dpp_round<0x141>(v, i);   // row_half_mirror (merge 4-groups)
    dpp_round<0x140>(v, i);   // row_mirror      (merge 8-groups)
}

// wv0: reduce the 32 row-bests and publish the block best as one tagged
// relaxed 64-bit agent-scope word.
__device__ __forceinline__ void reduce_publish(const uint64_t* red, uint64_t* sb,
                                               uint32_t tag, int lane, int member) {
    uint64_t c = red[lane & 31];
    float v  = u2f((uint32_t)(c >> 32));
    int   ix = (int)(uint32_t)(c & 0xFFFFFFFFu);
    row16_argmax(v, ix);      // rows reduce entries 0..15 / 16..31 (dup'd)
    swz16_round(v, ix);       // merge halves -> block best on all lanes
    if (lane == 0) {
        uint64_t w = ((uint64_t)f2u(v) << 32)
                   | ((uint64_t)(uint32_t)ix << 16) | tag;
        __hip_atomic_store(&sb[member], w, __ATOMIC_RELAXED,
                           __HIP_MEMORY_SCOPE_AGENT);
    }
}

// wv1: poll the 16 member slots (lane l watches slot l&15) until every slot
// carries this step's tag; reduce to the global winner (all lanes get it).
__device__ __forceinline__ void poll_line(const uint64_t* sb, uint32_t tag,
                                          int lane, float& gv, int& gi) {
    uint64_t w = 0; bool done = false;
    do {
        if (!done) w = __hip_atomic_load(&sb[lane & 15], __ATOMIC_RELAXED,
                                         __HIP_MEMORY_SCOPE_AGENT);
        done = (uint32_t)(w & 0xFFFFu) == tag;
    } while (!__all(done));
    gv = u2f((uint32_t)(w >> 32));
    gi = (int)((w >> 16) & 0xFFFFu);
    row16_argmax(gv, gi);     // each row covers all 16 slots -> global winner
}

// dist-update + per-thread argmax + row16 + red write (first-occurrence:
// strict >, ascending k = ascending global index; cross-lane ties resolved
// by min-index amerge).
#define COMPUTE_PHASE(sx, py, pz, pd, bc, red)                              \
    {                                                                       \
        float cx = u2f(bc[0]), cy = u2f(bc[1]), cz = u2f(bc[2]);            \
        float bv = -1.0f; int bk = 0;                                       \
        _Pragma("unroll")                                                   \
        for (int k = 0; k < PPT; ++k) {                                     \
            int p = tid + k * NTHREADS;                                     \
            float dx = sx[p] - cx;                                          \
            float dy = py[k] - cy;                                          \
            float dz = pz[k] - cz;                                          \
            float d  = dx * dx + dy * dy;  /* contract(off): mul,mul,add */ \
            d = d + dz * dz;               /* then add - numpy order */     \
            float nd = fminf(pd[k], d);                                     \
            pd[k] = nd;                                                     \
            bool g = nd > bv;                                               \
            bv = fmaxf(bv, nd);                                             \
            bk = g ? k : bk;                                                \
        }                                                                   \
        int bi = gbase + tid + (bk << 9);                                   \
        row16_argmax(bv, bi);                                               \
        if ((lane & 15) == 0)                                               \
            red[wv * 4 + (lane >> 4)] =                                     \
                ((uint64_t)f2u(bv) << 32) | (uint32_t)bi;                   \
    }

__global__ void __launch_bounds__(NTHREADS)
fps_kernel(const float* __restrict__ xyz, int* __restrict__ out,
           uint64_t* __restrict__ cand)
{
    // x in LDS purely as register relief: each thread touches only its own
    // slots (p = tid + k*512) -> no barriers for sx, conflict-free.
    __shared__ float    sxA[CHUNK], sxB[CHUNK];   // 16 KB + 16 KB
    __shared__ uint64_t redA[32], redB[32];
    __shared__ uint32_t bcA[4], bcB[4];

    // 256 blocks = 16 groups x 16 members; each group runs TWO batches
    // pipelined. Members of a group share i%16 residue (same-XCD heuristic
    // under round-robin dispatch; correctness relies only on agent-scope ops).
    const int i = blockIdx.x;           // [0, 256)
    const int member = i >> 4;          // [0,16)
    const int group  = i & 15;          // [0,16)
    const int batchA = group * 2;
    const int batchB = group * 2 + 1;
    const int tid  = threadIdx.x;
    const int lane = tid & 63;
    const int wv   = tid >> 6;

    const float* xbA = xyz + (size_t)batchA * 3 * NPTS;
    const float* xbB = xyz + (size_t)batchB * 3 * NPTS;
    const int gbase = member * CHUNK;

    float pyA[PPT], pzA[PPT], pdA[PPT];   // 2 x 24 data floats
    float pyB[PPT], pzB[PPT], pdB[PPT];
#pragma unroll
    for (int k = 0; k < PPT; ++k) {
        int p = tid + k * NTHREADS;
        int g = gbase + p;
        sxA[p] = xbA[g];
        pyA[k] = xbA[NPTS + g];
        pzA[k] = xbA[2 * NPTS + g];
        pdA[k] = 1e10f;
        sxB[p] = xbB[g];
        pyB[k] = xbB[NPTS + g];
        pzB[k] = xbB[2 * NPTS + g];
        pdB[k] = 1e10f;
    }

    // First centroid of each batch is point 0; first emitted index is 0.
    if (tid == 0) {
        bcA[0] = f2u(xbA[0]); bcA[1] = f2u(xbA[NPTS]); bcA[2] = f2u(xbA[2 * NPTS]);
        bcB[0] = f2u(xbB[0]); bcB[1] = f2u(xbB[NPTS]); bcB[2] = f2u(xbB[2 * NPTS]);
        if (member == 0) {
            out[(size_t)batchA * NPT] = 0;
            out[(size_t)batchB * NPT] = 0;
        }
    }
    __syncthreads();

    // cand[batch][parity][LINEPAD]: 16 live 8B slots in a padded 256B slab.
    uint64_t* cbA = cand + (size_t)batchA * 2 * LINEPAD;
    uint64_t* cbB = cand + (size_t)batchB * 2 * LINEPAD;

    // Pipelined double-FPS loop. Tag t = candidates computed against the
    // step-t centroid (they decide step t+1). ABA-safe: publish of tag t+2
    // into a parity slot is transitively gated on every member passing the
    // poll of tag t (program order + barriers). Poison (0xAAAA) / previous
    // -replay tags (2046/2045) never match the first polled tags -> no memset.
    for (int t = 0; t < NPT - 1; ++t) {
        const uint32_t tag = (uint32_t)t;

        // ---- P1: compute A(t) ----
        COMPUTE_PHASE(sxA, pyA, pzA, pdA, bcA, redA);
        __syncthreads();

        // ---- P2: publish A(t) || poll B(t-1) ----
        if (wv == 0) {
            __builtin_amdgcn_s_setprio(1);
            reduce_publish(redA, cbA + (size_t)(t & 1) * LINEPAD, tag, lane, member);
            __builtin_amdgcn_s_setprio(0);
        } else if (wv == 1 && t > 0) {
            __builtin_amdgcn_s_setprio(1);
            float gv; int gi;
            poll_line(cbB + (size_t)((t - 1) & 1) * LINEPAD, (uint32_t)(t - 1),
                      lane, gv, gi);
            if (lane < 3) bcB[lane] = f2u(xbB[(size_t)lane * NPTS + gi]);
            if (lane == 0 && member == 0) out[(size_t)batchB * NPT + t] = gi;
            __builtin_amdgcn_s_setprio(0);
        }
        __syncthreads();

        // ---- P3: compute B(t) ----
        COMPUTE_PHASE(sxB, pyB, pzB, pdB, bcB, redB);
        __syncthreads();

        // ---- P4: publish B(t) || poll A(t) ----
        if (wv == 0) {
            __builtin_amdgcn_s_setprio(1);
            reduce_publish(redB, cbB + (size_t)(t & 1) * LINEPAD, tag, lane, member);
            __builtin_amdgcn_s_setprio(0);
        } else if (wv == 1) {
            __builtin_amdgcn_s_setprio(1);
            float gv; int gi;
            poll_line(cbA + (size_t)(t & 1) * LINEPAD, tag, lane, gv, gi);
            if (lane < 3) bcA[lane] = f2u(xbA[(size_t)lane * NPTS + gi]);
            if (lane == 0 && member == 0) out[(size_t)batchA * NPT + t + 1] = gi;
            __builtin_amdgcn_s_setprio(0);
        }
        __syncthreads();
    }

    // ---- epilogue: B's final winner (tag NPT-2) -> out_B[NPT-1] ----
    if (member == 0 && wv == 1) {
        const uint32_t tag = NPT - 2;
        float gv; int gi;
        poll_line(cbB + (size_t)(tag & 1) * LINEPAD, tag, lane, gv, gi);
        if (lane == 0) out[(size_t)batchB * NPT + NPT - 1] = gi;
    }
}

extern "C" void kernel_launch(void* const* d_in, const int* in_sizes, int n_in,
                              void* d_out, int out_size, void* d_ws, size_t ws_size,
                              hipStream_t stream)
{
    const float* xyz = (const float*)d_in[0];
    int* out = (int*)d_out;
    uint64_t* cand = (uint64_t*)d_ws;   // 32*2*32*8 = 16 KiB used; no memset needed
    fps_kernel<<<NGROUPS * MEMBERS, NTHREADS, 0, stream>>>(xyz, out, cand);
}

// Round 12
// 5329.717 us; speedup vs baseline: 1.0442x; 1.0442x over previous
//
#include <hip/hip_runtime.h>
#include <stdint.h>

// Must match numpy float32 rounding exactly: (dx*dx + dy*dy) + dz*dz, no FMA.
#pragma clang fp contract(off)

#define NPT      2048
#define NBATCH   32
#define NPTS     65536
#define MEMBERS  16
#define NGROUPS  (NBATCH / 2)           // 16 groups x 2 batches each
#define NTHREADS 512
#define CHUNK    (NPTS / MEMBERS)       // 4096 points per block per batch
#define PPT      (CHUNK / NTHREADS)     // 8 points per thread per batch
#define WPB      (NTHREADS / 64)        // 8 waves per block
#define LINEPAD  32                     // 256B per (batch,parity) slot line

__device__ __forceinline__ uint32_t f2u(float f) { return __float_as_uint(f); }
__device__ __forceinline__ float u2f(uint32_t u) { return __uint_as_float(u); }

// argmax combine: larger value wins; tie -> smaller index (numpy argmax order)
__device__ __forceinline__ void amerge(float& v, int& i, float ov, int oi) {
    if (ov > v || (ov == v && oi < i)) { v = ov; i = oi; }
}
template<int CTRL>
__device__ __forceinline__ void dpp_round(float& v, int& i) {
    float ov = u2f((uint32_t)__builtin_amdgcn_mov_dpp((int)f2u(v), CTRL, 0xf, 0xf, true));
    int   oi = __builtin_amdgcn_mov_dpp(i, CTRL, 0xf, 0xf, true);
    amerge(v, i, ov, oi);
}
__device__ __forceinline__ void swz16_round(float& v, int& i) {   // lane ^ 16
    float ov = u2f((uint32_t)__builtin_amdgcn_ds_swizzle((int)f2u(v), 0x401F));
    int   oi = __builtin_amdgcn_ds_swizzle(i, 0x401F);
    amerge(v, i, ov, oi);
}
// reduce within each row of 16 lanes (slots/entries replicated per row)
__device__ __forceinline__ void row16_argmax(float& v, int& i) {
    dpp_round<0xB1>(v, i);    // quad_perm xor1
    dpp_round<0x4E>(v, i);    // quad_perm xor2
    dpp_round<0x141>(v, i);   // row_half_mirror (merge 4-groups)
    dpp_round<0x140>(v, i);   // row_mirror      (merge 8-groups)
}

// reduce the 32 row-bests and publish the block best as one tagged relaxed
// 64-bit agent-scope word into this member's slot.
__device__ __forceinline__ void reduce_publish(const uint64_t* red, uint64_t* sb,
                                               uint32_t tag, int lane, int member) {
    uint64_t c = red[lane & 31];
    float v  = u2f((uint32_t)(c >> 32));
    int   ix = (int)(uint32_t)(c & 0xFFFFFFFFu);
    row16_argmax(v, ix);      // rows reduce entries 0..15 / 16..31 (dup'd)
    swz16_round(v, ix);       // merge halves -> block best on all lanes
    if (lane == 0) {
        uint64_t w = ((uint64_t)f2u(v) << 32)
                   | ((uint64_t)(uint32_t)ix << 16) | tag;
        __hip_atomic_store(&sb[member], w, __ATOMIC_RELAXED,
                           __HIP_MEMORY_SCOPE_AGENT);
    }
}

// poll the 16 member slots (lane l watches slot l&15) until every slot
// carries this step's tag; reduce to the global winner (all lanes get it).
__device__ __forceinline__ void poll_line(const uint64_t* sb, uint32_t tag,
                                          int lane, float& gv, int& gi) {
    uint64_t w = 0; bool done = false;
    do {
        if (!done) w = __hip_atomic_load(&sb[lane & 15], __ATOMIC_RELAXED,
                                         __HIP_MEMORY_SCOPE_AGENT);
        done = (uint32_t)(w & 0xFFFFu) == tag;
    } while (!__all(done));
    gv = u2f((uint32_t)(w >> 32));
    gi = (int)((w >> 16) & 0xFFFFu);
    row16_argmax(gv, gi);     // each row covers all 16 slots -> global winner
}

// dist-update + per-thread argmax + row16 + red write (first-occurrence:
// strict >, ascending k = ascending global index; cross-lane ties resolved
// by min-index amerge).
#define COMPUTE_PHASE(sx, py, pz, pd, bc, red)                              \
    {                                                                       \
        float cx = u2f(bc[0]), cy = u2f(bc[1]), cz = u2f(bc[2]);            \
        float bv = -1.0f; int bk = 0;                                       \
        _Pragma("unroll")                                                   \
        for (int k = 0; k < PPT; ++k) {                                     \
            int p = tid + k * NTHREADS;                                     \
            float dx = sx[p] - cx;                                          \
            float dy = py[k] - cy;                                          \
            float dz = pz[k] - cz;                                          \
            float d  = dx * dx + dy * dy;  /* contract(off): mul,mul,add */ \
            d = d + dz * dz;               /* then add - numpy order */     \
            float nd = fminf(pd[k], d);                                     \
            pd[k] = nd;                                                     \
            bool g = nd > bv;                                               \
            bv = fmaxf(bv, nd);                                             \
            bk = g ? k : bk;                                                \
        }                                                                   \
        int bi = gbase + tid + (bk << 9);                                   \
        row16_argmax(bv, bi);                                               \
        if ((lane & 15) == 0)                                               \
            red[wv * 4 + (lane >> 4)] =                                     \
                ((uint64_t)f2u(bv) << 32) | (uint32_t)bi;                   \
    }

__global__ void __launch_bounds__(NTHREADS)
fps_kernel(const float* __restrict__ xyz, int* __restrict__ out,
           uint64_t* __restrict__ cand)
{
    // x in LDS purely as register relief: each thread touches only its own
    // slots (p = tid + k*512) -> no barriers for sx, conflict-free.
    __shared__ float    sxA[CHUNK], sxB[CHUNK];   // 16 KB + 16 KB
    __shared__ uint64_t redA[32], redB[32];
    __shared__ uint32_t bcA[4], bcB[4];

    // 256 blocks = 16 groups x 16 members; each group runs TWO batches.
    // Members of a group share i%16 residue (same-XCD heuristic under
    // round-robin dispatch; correctness relies only on agent-scope ops).
    const int i = blockIdx.x;           // [0, 256)
    const int member = i >> 4;          // [0,16)
    const int group  = i & 15;          // [0,16)
    const int batchA = group * 2;
    const int batchB = group * 2 + 1;
    const int tid  = threadIdx.x;
    const int lane = tid & 63;
    const int wv   = tid >> 6;

    const float* xbA = xyz + (size_t)batchA * 3 * NPTS;
    const float* xbB = xyz + (size_t)batchB * 3 * NPTS;
    const int gbase = member * CHUNK;

    float pyA[PPT], pzA[PPT], pdA[PPT];   // 2 x 24 data floats
    float pyB[PPT], pzB[PPT], pdB[PPT];
#pragma unroll
    for (int k = 0; k < PPT; ++k) {
        int p = tid + k * NTHREADS;
        int g = gbase + p;
        sxA[p] = xbA[g];
        pyA[k] = xbA[NPTS + g];
        pzA[k] = xbA[2 * NPTS + g];
        pdA[k] = 1e10f;
        sxB[p] = xbB[g];
        pyB[k] = xbB[NPTS + g];
        pzB[k] = xbB[2 * NPTS + g];
        pdB[k] = 1e10f;
    }

    // First centroid of each batch is point 0; first emitted index is 0.
    if (tid == 0) {
        bcA[0] = f2u(xbA[0]); bcA[1] = f2u(xbA[NPTS]); bcA[2] = f2u(xbA[2 * NPTS]);
        bcB[0] = f2u(xbB[0]); bcB[1] = f2u(xbB[NPTS]); bcB[2] = f2u(xbB[2 * NPTS]);
        if (member == 0) {
            out[(size_t)batchA * NPT] = 0;
            out[(size_t)batchB * NPT] = 0;
        }
    }
    __syncthreads();

    // cand[batch][parity][LINEPAD]: 16 live 8B slots in a padded 256B slab.
    uint64_t* cbA = cand + (size_t)batchA * 2 * LINEPAD;
    uint64_t* cbB = cand + (size_t)batchB * 2 * LINEPAD;

    // Per iteration both batches advance one step; the two publish->poll
    // round trips run CONCURRENTLY (wv0 handles A, wv1 handles B) so only
    // one RT appears in the period. ABA-safe: member m publishes tag t+2
    // only after its poll(t+1) completed, which required every member's
    // publish(t+1), which follows their poll(t) -> all reads of tag t done
    // before any overwrite. Poison (0xAAAA) / prior-replay tags (2045/2046)
    // never match the first polled tags -> no memset needed.
    for (int t = 0; t < NPT - 1; ++t) {
        const uint32_t tag = (uint32_t)t;

        // ---- P1: compute A(t) ----
        COMPUTE_PHASE(sxA, pyA, pzA, pdA, bcA, redA);
        __syncthreads();

        // ---- P2: compute B(t) ----
        COMPUTE_PHASE(sxB, pyB, pzB, pdB, bcB, redB);
        __syncthreads();

        // ---- P3: publish+poll A (wv0) || publish+poll B (wv1) ----
        if (wv == 0) {
            __builtin_amdgcn_s_setprio(1);
            uint64_t* sbA = cbA + (size_t)(t & 1) * LINEPAD;
            reduce_publish(redA, sbA, tag, lane, member);
            float gv; int gi;
            poll_line(sbA, tag, lane, gv, gi);
            if (lane < 3) bcA[lane] = f2u(xbA[(size_t)lane * NPTS + gi]);
            if (lane == 0 && member == 0) out[(size_t)batchA * NPT + t + 1] = gi;
            __builtin_amdgcn_s_setprio(0);
        } else if (wv == 1) {
            __builtin_amdgcn_s_setprio(1);
            uint64_t* sbB = cbB + (size_t)(t & 1) * LINEPAD;
            reduce_publish(redB, sbB, tag, lane, member);
            float gv; int gi;
            poll_line(sbB, tag, lane, gv, gi);
            if (lane < 3) bcB[lane] = f2u(xbB[(size_t)lane * NPTS + gi]);
            if (lane == 0 && member == 0) out[(size_t)batchB * NPT + t + 1] = gi;
            __builtin_amdgcn_s_setprio(0);
        }
        __syncthreads();
    }
}

extern "C" void kernel_launch(void* const* d_in, const int* in_sizes, int n_in,
                              void* d_out, int out_size, void* d_ws, size_t ws_size,
                              hipStream_t stream)
{
    const float* xyz = (const float*)d_in[0];
    int* out = (int*)d_out;
    uint64_t* cand = (uint64_t*)d_ws;   // 32*2*32*8 = 16 KiB used; no memset needed
    fps_kernel<<<NGROUPS * MEMBERS, NTHREADS, 0, stream>>>(xyz, out, cand);
}

// Round 13
// 5118.990 us; speedup vs baseline: 1.0872x; 1.0412x over previous
//
#include <hip/hip_runtime.h>
#include <stdint.h>

// Must match numpy float32 rounding exactly: (dx*dx + dy*dy) + dz*dz, no FMA.
#pragma clang fp contract(off)

#define NPT      2048
#define NBATCH   32
#define NPTS     65536
#define MEMBERS  8
#define NTHREADS 1024
#define CHUNK    (NPTS / MEMBERS)       // 8192 points per block
#define PPT      (CHUNK / NTHREADS)     // 8 points per thread
#define WPB      (NTHREADS / 64)        // 16 waves per block
#define LINEPAD  16                     // 128B per (batch,parity) slot line

__device__ __forceinline__ uint32_t f2u(float f) { return __float_as_uint(f); }
__device__ __forceinline__ float u2f(uint32_t u) { return __uint_as_float(u); }

// argmax combine: larger value wins; tie -> smaller index (numpy argmax order)
__device__ __forceinline__ void amerge(float& v, int& i, float ov, int oi) {
    if (ov > v || (ov == v && oi < i)) { v = ov; i = oi; }
}
template<int CTRL>
__device__ __forceinline__ void dpp_round(float& v, int& i) {
    float ov = u2f((uint32_t)__builtin_amdgcn_mov_dpp((int)f2u(v), CTRL, 0xf, 0xf, true));
    int   oi = __builtin_amdgcn_mov_dpp(i, CTRL, 0xf, 0xf, true);
    amerge(v, i, ov, oi);
}
__device__ __forceinline__ void swz16_round(float& v, int& i) {   // lane ^ 16
    float ov = u2f((uint32_t)__builtin_amdgcn_ds_swizzle((int)f2u(v), 0x401F));
    int   oi = __builtin_amdgcn_ds_swizzle(i, 0x401F);
    amerge(v, i, ov, oi);
}
__device__ __forceinline__ void shfl32_round(float& v, int& i) {  // lane ^ 32
    float ov = __shfl_xor(v, 32, 64);
    int   oi = __shfl_xor(i, 32, 64);
    amerge(v, i, ov, oi);
}
// full 64-lane argmax
__device__ __forceinline__ void wave_argmax(float& v, int& i) {
    dpp_round<0xB1>(v, i);    // quad_perm xor1
    dpp_round<0x4E>(v, i);    // quad_perm xor2
    dpp_round<0x141>(v, i);   // row_half_mirror
    dpp_round<0x140>(v, i);   // row_mirror
    swz16_round(v, i);        // xor16
    shfl32_round(v, i);       // xor32
}
// reduce within each row of 16 lanes (entries replicated per row)
__device__ __forceinline__ void row16_argmax(float& v, int& i) {
    dpp_round<0xB1>(v, i);
    dpp_round<0x4E>(v, i);
    dpp_round<0x141>(v, i);
    dpp_round<0x140>(v, i);
}
// reduce over 8 candidates held at slot (lane&7)
__device__ __forceinline__ void oct_argmax(float& v, int& i) {
    dpp_round<0xB1>(v, i);
    dpp_round<0x4E>(v, i);
    dpp_round<0x141>(v, i);
}

__global__ void __launch_bounds__(NTHREADS)
fps_kernel(const float* __restrict__ xyz, int* __restrict__ out,
           uint64_t* __restrict__ cand)
{
    // x in LDS purely as register relief: each thread touches only its own
    // 8 slots (p = tid + k*1024) -> conflict-free, no sync needed after init.
    __shared__ float    sx[CHUNK];       // 32 KB
    __shared__ uint64_t red[2][WPB];     // tagged wave-best mailboxes (parity)
    __shared__ uint32_t bc[2][4];        // {x,y,z,flag} per parity

    // Swizzle: a batch's 8 members share blockIdx%8 (XCD heuristic only;
    // correctness relies solely on agent-scope coherence-point ops).
    const int i = blockIdx.x;
    const int q = i >> 3;
    const int batch  = (i & 7) * 4 + (q & 3);   // [0,32)
    const int member = q >> 2;                  // [0,8)
    const int tid  = threadIdx.x;
    const int lane = tid & 63;
    const int wv   = tid >> 6;

    const float* xb = xyz + (size_t)batch * 3 * NPTS;
    const int gbase = member * CHUNK;

    float py[PPT], pz[PPT], pd[PPT];    // 24 data floats
#pragma unroll
    for (int k = 0; k < PPT; ++k) {
        int p = tid + k * NTHREADS;
        int g = gbase + p;
        sx[p] = xb[g];
        py[k] = xb[NPTS + g];
        pz[k] = xb[2 * NPTS + g];
        pd[k] = 1e10f;
    }

    // Init LDS protocol state (LDS contents are undefined at launch).
    if (tid == 0) {
        bc[0][0] = f2u(xb[0]); bc[0][1] = f2u(xb[NPTS]); bc[0][2] = f2u(xb[2 * NPTS]);
        bc[0][3] = 0;                // centroid for step 0 ready
        bc[1][3] = 0xFFFFFFFFu;      // parity-1 centroid not ready
        if (member == 0) out[(size_t)batch * NPT] = 0;
    }
    if (tid < 2 * WPB) red[tid >> 4][tid & 15] = ~0ull;   // invalid tags
    __syncthreads();   // the only block-wide barrier

    uint64_t* cb = cand + (size_t)batch * 2 * LINEPAD;
    volatile uint32_t* vbc0 = &bc[0][0];
    volatile uint32_t* vbc1 = &bc[1][0];

    for (int t = 0; t < NPT - 1; ++t) {
        const int par = t & 1;
        const uint32_t tag = (uint32_t)t;
        volatile uint32_t* vb = par ? vbc1 : vbc0;

        // ---- wait for this step's centroid (tagged LDS flag), read coords ----
        while (vb[3] != tag) {}
        float cx = u2f(vb[0]), cy = u2f(vb[1]), cz = u2f(vb[2]);

        // ---- dist update + per-thread argmax (strict >, ascending k =
        //      ascending global index -> first-occurrence semantics) ----
        float bv = -1.0f;            // all dists >= 0, so always beaten
        int   bk = 0;
#pragma unroll
        for (int k = 0; k < PPT; ++k) {
            int p = tid + k * NTHREADS;
            float dx = sx[p] - cx;
            float dy = py[k] - cy;
            float dz = pz[k] - cz;
            float d  = dx * dx + dy * dy;   // contract(off): mul,mul,add
            d = d + dz * dz;                // then add — matches numpy order
            float nd = fminf(pd[k], d);
            pd[k] = nd;
            bool g = nd > bv;
            bv = fmaxf(bv, nd);
            bk = g ? k : bk;
        }
        int bi = gbase + tid + (bk << 10);  // reconstruct global index

        // ---- per-wave argmax, publish wave-best into tagged LDS mailbox ----
        wave_argmax(bv, bi);
        if (lane == 0)
            ((volatile uint64_t*)&red[par][wv])[0] =
                ((uint64_t)f2u(bv) << 32) | ((uint64_t)(uint32_t)bi << 16) | tag;

        if (wv == 0) {
            __builtin_amdgcn_s_setprio(1);
            // ---- scan the 16 wave mailboxes (tag-gated, no barrier) ----
            uint64_t c; bool rok = false;
            do {
                c = ((volatile uint64_t*)&red[par][lane & 15])[0];
                rok = (uint32_t)(c & 0xFFFFu) == tag;
            } while (!__all(rok));
            float v  = u2f((uint32_t)(c >> 32));
            int   ix = (int)((c >> 16) & 0xFFFFu);
            row16_argmax(v, ix);     // block best on all lanes

            // ---- publish block-best as one tagged relaxed agent word ----
            // ABA-safe (parity + monotone tags; rewrite at t+2 gated on all
            // members passing poll(t+1)); poison (0xAAAA) / prior-replay tags
            // (2046/2045) never match the first polls -> no memset needed.
            uint64_t* sb = cb + (size_t)par * LINEPAD;
            if (lane == 0) {
                uint64_t w = ((uint64_t)f2u(v) << 32)
                           | ((uint64_t)(uint32_t)ix << 16) | tag;
                __hip_atomic_store(&sb[member], w, __ATOMIC_RELAXED,
                                   __HIP_MEMORY_SCOPE_AGENT);
            }

            // ---- poll the 8 member slots; lanes 0-7 speculatively prefetch
            //      their slot-candidate's coords as soon as it arrives, so the
            //      winner's coords overlap the straggler wait.
            uint64_t* ap = &sb[lane & 7];
            uint64_t w = 0; bool done = false, fetched = false;
            float wx = 0.f, wy = 0.f, wz = 0.f; int mi = -1;
            do {
                if (!done) {
                    uint64_t x = __hip_atomic_load(ap, __ATOMIC_RELAXED,
                                                   __HIP_MEMORY_SCOPE_AGENT);
                    if ((uint32_t)(x & 0xFFFFu) == tag) { w = x; done = true; }
                }
                if (done && !fetched) {
                    fetched = true;
                    if (lane < 8) {
                        mi = (int)((w >> 16) & 0xFFFFu);
                        wx = xb[mi]; wy = xb[NPTS + mi]; wz = xb[2 * NPTS + mi];
                    }
                }
            } while (!__all(done));

            // ---- global argmax across the 8 member candidates ----
            float gv = u2f((uint32_t)(w >> 32));
            int   gi = (int)((w >> 16) & 0xFFFFu);
            oct_argmax(gv, gi);

            // winner's coords from the lane that prefetched them
            uint64_t mk = __ballot(mi == gi);
            int wl = (int)(__ffsll((unsigned long long)mk) - 1);
            float fx = __shfl(wx, wl, 64);
            float fy = __shfl(wy, wl, 64);
            float fz = __shfl(wz, wl, 64);

            if (lane == 0) {
                if (member == 0) out[(size_t)batch * NPT + t + 1] = gi;
                // next centroid broadcast: coords first, fence, then flag
                volatile uint32_t* nb = (par ^ 1) ? vbc1 : vbc0;
                nb[0] = f2u(fx); nb[1] = f2u(fy); nb[2] = f2u(fz);
                __threadfence_block();
                nb[3] = tag + 1;
            }
            __builtin_amdgcn_s_setprio(0);
        }
        // non-wv0 waves loop back and spin on the next centroid flag
    }
}

extern "C" void kernel_launch(void* const* d_in, const int* in_sizes, int n_in,
                              void* d_out, int out_size, void* d_ws, size_t ws_size,
                              hipStream_t stream)
{
    const float* xyz = (const float*)d_in[0];
    int* out = (int*)d_out;
    uint64_t* cand = (uint64_t*)d_ws;   // 32*2*16*8 = 8 KiB used; no memset needed
    fps_kernel<<<NBATCH * MEMBERS, NTHREADS, 0, stream>>>(xyz, out, cand);
}